// Round 8
// baseline (2528.018 us; speedup 1.0000x reference)
//
#include <hip/hip_runtime.h>

typedef unsigned short u16;
typedef unsigned int u32;
typedef float f32x4 __attribute__((ext_vector_type(4)));
typedef __bf16 bf16x8 __attribute__((ext_vector_type(8)));
typedef u16 u16x8 __attribute__((ext_vector_type(8)));

__device__ __forceinline__ float bf2f(u16 v) {
  union { u32 u; float f; } c; c.u = ((u32)v) << 16; return c.f;
}
__device__ __forceinline__ u16 f2bf(float f) {
  union { float f; u32 u; } c; c.f = f;
  c.u += 0x7fffu + ((c.u >> 16) & 1u);
  return (u16)(c.u >> 16);
}
__device__ __forceinline__ float fast_tanh(float x) {
  float e = __expf(2.0f * x);
  return 1.0f - 2.0f / (e + 1.0f);   // NaN-safe at +/-inf of e
}
__device__ __forceinline__ void gload16(const void* g, void* l) {
  __builtin_amdgcn_global_load_lds((const __attribute__((address_space(1))) void*)g,
                                   (__attribute__((address_space(3))) void*)l, 16, 0, 0);
}
__device__ __forceinline__ bf16x8 ldfrag(const u16* p) {
  return __builtin_bit_cast(bf16x8, *(const u16x8*)p);
}
// raw barrier with compiler memory fences (raw s_barrier has no IR fence)
__device__ __forceinline__ void BAR() {
  asm volatile("" ::: "memory");
  __builtin_amdgcn_s_barrier();
  asm volatile("" ::: "memory");
}
// Bijective XCD swizzle (m204): XCD x owns a contiguous range of logical ids.
__device__ __forceinline__ int xcd_swizzle() {
  const int nwg = (int)gridDim.x, orig = (int)blockIdx.x;
  const int q = nwg >> 3, r = nwg & 7;
  const int xcd = orig & 7, idx = orig >> 3;
  return (xcd < r ? xcd * (q + 1) : r * (q + 1) + (xcd - r) * q) + idx;
}

// ---------------------------------------------------------------- prep kernels
__global__ __launch_bounds__(256) void conv_bf(const float* __restrict__ s,
                                               u16* __restrict__ d, long n) {
  const long i = (long)blockIdx.x * 256 + threadIdx.x;
  if (i < n) d[i] = f2bf(s[i]);
}

__global__ __launch_bounds__(256) void trans_conv(const float* __restrict__ src,
                                                  u16* __restrict__ dst,
                                                  int K, int N, int batch) {
  const long total = (long)batch * K * N;
  const long idx = (long)blockIdx.x * 256 + threadIdx.x;
  if (idx >= total) return;
  const long l = idx / ((long)K * N);
  const long rem = idx - l * (long)K * N;
  const int n = (int)(rem / K);
  const int k = (int)(rem - (long)n * K);
  dst[idx] = f2bf(src[l * (long)K * N + (long)k * N + n]);
}

__global__ __launch_bounds__(256) void transf32(const float* __restrict__ src,
                                                float* __restrict__ dst) {
  const long idx = (long)blockIdx.x * 256 + threadIdx.x;  // 3*512*512
  const long l = idx >> 18;
  const int rem = (int)(idx & 262143);
  const int n = rem >> 9, a = rem & 511;
  dst[idx] = src[l * 262144 + (long)a * 512 + n];
}

__global__ __launch_bounds__(256) void build_quat(const float* __restrict__ wr,
                                                  const float* __restrict__ wi,
                                                  const float* __restrict__ wj,
                                                  const float* __restrict__ wk,
                                                  u16* __restrict__ dst) {
  const int idx = blockIdx.x * 256 + threadIdx.x;   // n*512+k
  const int n = idx >> 9, k = idx & 511;
  const int kb = k >> 7, kc = k & 127, nb = n >> 7, nc = n & 127;
  const float* const srcs[4] = {wr, wi, wj, wk};
  const float sgn[4][4] = {{1,1,1,1},{-1,1,-1,1},{-1,1,1,-1},{-1,-1,1,1}};
  dst[idx] = f2bf(sgn[kb][nb] * srcs[kb ^ nb][kc * 128 + nc]);
}

__global__ __launch_bounds__(256) void build_wav(const float* __restrict__ lo,
                                                 const float* __restrict__ hi,
                                                 u16* __restrict__ dst) {
  const int idx = blockIdx.x * 256 + threadIdx.x;   // n*512+k
  const int n = idx >> 9, k = idx & 511;
  const int d = k >> 1, c = n >> 1;
  const float a = lo[d * 256 + c], b = hi[d * 256 + c];
  dst[idx] = f2bf(((k ^ n) & 1) ? 0.5f * (a - b) : 0.5f * (a + b));
}

// Weight folds (f32 NT-GEMM, 64x64 tile): C[n][k] = sum_a L[n][a]*R[k][a] -> bf16.
__global__ __launch_bounds__(256) void fold_nt(const float* __restrict__ Wq,
                                               const float* __restrict__ Wk,
                                               const float* __restrict__ Wv,
                                               const float* __restrict__ WoT,
                                               u16* __restrict__ dst) {
  const int bx = blockIdx.x;
  const int slot = bx >> 6, l = slot >> 1, isvo = slot & 1;
  const float* L = isvo ? WoT + (size_t)l * 262144 : Wk + (size_t)l * 262144;
  const float* R = isvo ? Wv + (size_t)l * 262144 : Wq + (size_t)l * 262144;
  u16* D = dst + (size_t)l * 524288 + (size_t)isvo * 262144;
  const int t = bx & 63;
  const int n0 = (t >> 3) << 6, k0 = (t & 7) << 6;
  __shared__ float Lt[64][65];
  __shared__ float Rt[64][65];
  const int tid = threadIdx.x;
  const int tr = tid >> 4, tc = tid & 15;
  float acc[4][4] = {};
  for (int a0 = 0; a0 < 512; a0 += 64) {
    __syncthreads();
    #pragma unroll
    for (int r = 0; r < 4; ++r) {
      const int idx = r * 256 + tid;
      const int row = idx >> 4, c4 = (idx & 15) << 2;
      const f32x4 lv = *(const f32x4*)&L[(size_t)(n0 + row) * 512 + a0 + c4];
      const f32x4 rv = *(const f32x4*)&R[(size_t)(k0 + row) * 512 + a0 + c4];
      #pragma unroll
      for (int u = 0; u < 4; ++u) { Lt[row][c4 + u] = lv[u]; Rt[row][c4 + u] = rv[u]; }
    }
    __syncthreads();
    #pragma unroll 4
    for (int kk = 0; kk < 64; ++kk) {
      float lv[4], rv[4];
      #pragma unroll
      for (int i = 0; i < 4; ++i) lv[i] = Lt[tr * 4 + i][kk];
      #pragma unroll
      for (int j = 0; j < 4; ++j) rv[j] = Rt[tc * 4 + j][kk];
      #pragma unroll
      for (int i = 0; i < 4; ++i)
        #pragma unroll
        for (int j = 0; j < 4; ++j) acc[i][j] += lv[i] * rv[j];
    }
  }
  #pragma unroll
  for (int i = 0; i < 4; ++i)
    #pragma unroll
    for (int j = 0; j < 4; ++j)
      D[(size_t)(n0 + tr * 4 + i) * 512 + k0 + tc * 4 + j] = f2bf(acc[i][j]);
}

// ---------------------------------------------------------------- GEMM 256x256
// 8 waves (2M x 4N), BK=64, per-wave 128x64 out (acc[8][4] f32x4). LDS 128 KB
// dbuf. Counted-vmcnt schedule (T3/T4): stage tile t+1 front-loaded, then
// vmcnt(8) keeps those 8 loads in flight across the raw s_barrier; 4 compute
// phases each {12 ds_read_b128; barrier; setprio(1); 16 MFMA; setprio(0);
// barrier}. LDS st_16x32 swizzle (T2) via inverse-swizzled global source
// (gload_lds writes linearly) -> 16-way bank conflict cut to 4-way.
// EPI: 0=none->bf16  1=bias+leaky->bf16  2=bias+tanh->bf16
template<int EPI>
__global__ __launch_bounds__(512, 2)
void gemm256(const u16* __restrict__ A, const u16* __restrict__ BT,
             u16* __restrict__ C, const float* __restrict__ bias,
             int N, int K) {
  __shared__ u16 L[65536];                       // [2 par][A 16K u16 | B 16K u16]
  const int tid = threadIdx.x;
  const int nblk = N >> 8;
  const int bx = xcd_swizzle();
  const int bm = bx / nblk, bn = bx % nblk;      // bn-major + XCD swizzle
  const long m0 = (long)bm << 8;
  const int n0 = bn << 8;
  const int wid = tid >> 6, lane = tid & 63;
  const int wr = wid >> 2, wc = wid & 3;         // 2M x 4N waves
  const int lr = lane & 15, lg = lane >> 4;
  const int innerU16 = lr * 32 + ((lg * 8) ^ ((lr & 8) ? 16 : 0));

  // staging decode: chunk c = tid + 512*j (16B each); logical (row,col) such
  // that linear LDS byte c*16 holds the swizzled layout (bijection verified)
  int srow[4], scol[4], sdst[4];
  #pragma unroll
  for (int j = 0; j < 4; ++j) {
    const int c = tid + 512 * j;
    const int s = c >> 6, w = c & 63, lrow = w >> 2;
    const int lcol = ((w & 3) * 8) ^ ((lrow & 8) ? 16 : 0);
    srow[j] = (s >> 1) * 16 + lrow;
    scol[j] = (s & 1) * 32 + lcol;
    sdst[j] = c * 8;                             // u16 offset in operand region
  }

  f32x4 acc[8][4];
  #pragma unroll
  for (int i = 0; i < 8; ++i)
    #pragma unroll
    for (int j = 0; j < 4; ++j) acc[i][j] = (f32x4){0.f, 0.f, 0.f, 0.f};

  const int NT = K >> 6;
  // prologue: stage tile 0 into parity 0
  #pragma unroll
  for (int j = 0; j < 4; ++j)
    gload16(A + (m0 + srow[j]) * (long)K + scol[j], &L[sdst[j]]);
  #pragma unroll
  for (int j = 0; j < 4; ++j)
    gload16(BT + (size_t)(n0 + srow[j]) * K + scol[j], &L[16384 + sdst[j]]);

  #pragma unroll 1
  for (int t = 0; t < NT; ++t) {
    const int par = t & 1;
    if (t + 1 < NT) {                            // stage t+1 (front-loaded)
      const int kt = (t + 1) << 6;
      const int pb = (par ^ 1) << 15;
      #pragma unroll
      for (int j = 0; j < 4; ++j)
        gload16(A + (m0 + srow[j]) * (long)K + kt + scol[j], &L[pb + sdst[j]]);
      #pragma unroll
      for (int j = 0; j < 4; ++j)
        gload16(BT + (size_t)(n0 + srow[j]) * K + kt + scol[j],
                &L[pb + 16384 + sdst[j]]);
      asm volatile("s_waitcnt vmcnt(8)" ::: "memory");  // t done, t+1 in flight
    } else {
      asm volatile("s_waitcnt vmcnt(0)" ::: "memory");
    }
    BAR();                                       // all waves: tile t LDS ready
    const u16* LA = &L[par << 15];
    const u16* LB = LA + 16384;
    #pragma unroll
    for (int p = 0; p < 4; ++p) {                // 4 phases, 16 MFMA each
      const int mq = (p >> 1) * 4, nq = (p & 1) * 2;
      bf16x8 af[2][4], bf[2][2];
      #pragma unroll
      for (int kkb = 0; kkb < 2; ++kkb) {
        #pragma unroll
        for (int i = 0; i < 4; ++i)
          af[kkb][i] = ldfrag(&LA[((wr * 8 + mq + i) * 2 + kkb) * 512 + innerU16]);
        #pragma unroll
        for (int n = 0; n < 2; ++n)
          bf[kkb][n] = ldfrag(&LB[((wc * 4 + nq + n) * 2 + kkb) * 512 + innerU16]);
      }
      BAR();
      __builtin_amdgcn_s_setprio(1);
      #pragma unroll
      for (int kkb = 0; kkb < 2; ++kkb)
        #pragma unroll
        for (int i = 0; i < 4; ++i)
          #pragma unroll
          for (int n = 0; n < 2; ++n)
            acc[mq + i][nq + n] = __builtin_amdgcn_mfma_f32_16x16x32_bf16(
                af[kkb][i], bf[kkb][n], acc[mq + i][nq + n], 0, 0, 0);
      __builtin_amdgcn_s_setprio(0);
      BAR();                                     // protects buf before restage
    }
  }

  // epilogue: C/D layout col=lane&15, row=(lane>>4)*4+reg
  #pragma unroll
  for (int m = 0; m < 8; ++m) {
    const long rbase = m0 + wr * 128 + m * 16 + lg * 4;
    #pragma unroll
    for (int n = 0; n < 4; ++n) {
      const int col = n0 + wc * 64 + n * 16 + lr;
      float bv = 0.f;
      if (EPI == 1 || EPI == 2) bv = bias[col];
      #pragma unroll
      for (int j = 0; j < 4; ++j) {
        float v = acc[m][n][j];
        if (EPI == 1) { v += bv; v = v > 0.f ? v : 0.01f * v; }
        if (EPI == 2) { v += bv; v = fast_tanh(v); }
        C[(rbase + j) * N + col] = f2bf(v);
      }
    }
  }
}

// ---------------------------------------------------------------- GEMM 128 (small N)
// m97 structure, kept for the final (M, N=128) projection only.
template<int EPI>
__global__ __launch_bounds__(256, 2)
void gemm_k(const u16* __restrict__ A, int arow, const u16* __restrict__ BT,
            u16* __restrict__ C, float* __restrict__ Cf,
            const float* __restrict__ bias, int N, int K) {
  __shared__ u16 lsA[128 * 64];
  __shared__ u16 lsB[128 * 64];
  const int tid = threadIdx.x;
  const int nblk = N >> 7;
  const int bx = xcd_swizzle();
  const int bm = bx / nblk;
  const int bn = bx % nblk;
  const long m0 = (long)bm << 7;
  const int n0 = bn << 7;
  const int w = tid >> 6, lane = tid & 63;
  const int wrow = ((w >> 1) & 1) << 6;
  const int wcol = (w & 1) << 6;
  const int lr = lane & 15, lg = lane >> 4;

  f32x4 acc[4][4];
  #pragma unroll
  for (int i = 0; i < 4; ++i)
    #pragma unroll
    for (int j = 0; j < 4; ++j) acc[i][j] = (f32x4){0.f, 0.f, 0.f, 0.f};

  for (int kt = 0; kt < K; kt += 64) {
    __syncthreads();
    #pragma unroll
    for (int r = 0; r < 4; ++r) {
      const int chunk = r * 256 + tid;
      const int row = chunk >> 3, cc = (chunk & 7) << 3;
      gload16(A + (m0 + row) * (long)arow + kt + cc, &lsA[chunk * 8]);
    }
    #pragma unroll
    for (int r = 0; r < 4; ++r) {
      const int chunk = r * 256 + tid;
      const int row = chunk >> 3, cc = (chunk & 7) << 3;
      gload16(BT + (size_t)(n0 + row) * K + kt + cc, &lsB[chunk * 8]);
    }
    __syncthreads();
    #pragma unroll
    for (int kk = 0; kk < 64; kk += 32) {
      bf16x8 af[4], bfr[4];
      #pragma unroll
      for (int m = 0; m < 4; ++m)
        af[m] = ldfrag(&lsA[(wrow + m * 16 + lr) * 64 + kk + lg * 8]);
      #pragma unroll
      for (int n = 0; n < 4; ++n)
        bfr[n] = ldfrag(&lsB[(wcol + n * 16 + lr) * 64 + kk + lg * 8]);
      #pragma unroll
      for (int m = 0; m < 4; ++m)
        #pragma unroll
        for (int n = 0; n < 4; ++n)
          acc[m][n] = __builtin_amdgcn_mfma_f32_16x16x32_bf16(
              af[m], bfr[n], acc[m][n], 0, 0, 0);
    }
  }
  #pragma unroll
  for (int m = 0; m < 4; ++m) {
    const long rbase = m0 + wrow + m * 16 + lg * 4;
    #pragma unroll
    for (int n = 0; n < 4; ++n) {
      const int col = n0 + wcol + n * 16 + lr;
      float bv = 0.f;
      if (EPI == 1 || EPI == 2 || EPI == 3) bv = bias[col];
      #pragma unroll
      for (int j = 0; j < 4; ++j) {
        float v = acc[m][n][j];
        const long row = rbase + j;
        if (EPI == 1) { v += bv; v = v > 0.f ? v : 0.01f * v; }
        if (EPI == 2) { v += bv; v = fast_tanh(v); }
        if (EPI == 3) { v += bv; }
        if (EPI == 3) Cf[row * N + col] = v;
        else          C[row * N + col] = f2bf(v);
      }
    }
  }
}

// ---------------------------------------------------------------- vortex agg
__global__ __launch_bounds__(256) void agg_k(const u16* __restrict__ z,
                                             u16* __restrict__ mo) {
  const long idx = (long)blockIdx.x * 256 + threadIdx.x;
  const int h0 = (int)(idx & 63) << 3;
  const long row = idx >> 6;
  const long b = row / 9;
  const int node = (int)(row - b * 9);
  const int srcn = (5 * node + 4) % 9;
  const u16x8 a = *(const u16x8*)&z[row * 512 + h0];
  const u16x8 c = *(const u16x8*)&z[(b * 9 + srcn) * 512 + h0];
  u16x8 o;
  #pragma unroll
  for (int u = 0; u < 8; ++u) o[u] = f2bf(0.5f * (bf2f(a[u]) + bf2f(c[u])));
  *(u16x8*)&mo[row * 512 + h0] = o;
}

// ---------------------------------------------------------------- fused attention
template<int MODE>
__global__ __launch_bounds__(256, 2)
void attn_fused(const u16* __restrict__ sv, const u16* __restrict__ z,
                const float* __restrict__ gamma, const float* __restrict__ beta,
                u16* __restrict__ outp) {
  __shared__ float laf[4][256];
  const int tid = threadIdx.x;
  const int wv = tid >> 6, lane = tid & 63;
  const long b = (long)blockIdx.x * 4 + wv;
  const long b9 = b * 9;
  const int lr = lane & 15, lg = lane >> 4;
  const int rr = lr > 8 ? 8 : lr;

  f32x4 sacc = {0.f, 0.f, 0.f, 0.f};
  const u16* srow = sv + (b9 + rr) * 1024;
  const u16* zrow = z + (b9 + rr) * 512;
  #pragma unroll
  for (int kc = 0; kc < 16; ++kc) {
    const bf16x8 qa = ldfrag(srow + kc * 32 + lg * 8);
    const bf16x8 kb = ldfrag(zrow + kc * 32 + lg * 8);
    sacc = __builtin_amdgcn_mfma_f32_16x16x32_bf16(qa, kb, sacc, 0, 0, 0);
  }
  const float scale = 0.0441941738241592f;      // 1/sqrt(512)
  #pragma unroll
  for (int r = 0; r < 4; ++r) {
    float s = sacc[r] * scale;
    if (lr > 8) s = -1e30f;
    float mx = s;
    #pragma unroll
    for (int m = 1; m < 16; m <<= 1) mx = fmaxf(mx, __shfl_xor(mx, m, 16));
    const float e = __expf(s - mx);
    float sum = e;
    #pragma unroll
    for (int m = 1; m < 16; m <<= 1) sum += __shfl_xor(sum, m, 16);
    laf[wv][(lg * 4 + r) * 16 + lr] = e / sum;
  }
  __syncthreads();

  constexpr int NR = (MODE == 0) ? 9 : 1;
  float o[NR][8];
  #pragma unroll
  for (int i = 0; i < NR; ++i)
    #pragma unroll
    for (int u = 0; u < 8; ++u) o[i][u] = 0.f;

  #pragma unroll
  for (int j = 0; j < 9; ++j) {
    const u16x8 v8 = *(const u16x8*)&sv[(b9 + j) * 1024 + 512 + lane * 8];
    float vf[8];
    #pragma unroll
    for (int u = 0; u < 8; ++u) vf[u] = bf2f(v8[u]);
    #pragma unroll
    for (int i = 0; i < NR; ++i) {
      const float aij = laf[wv][((MODE == 0) ? i : 8) * 16 + j];
      #pragma unroll
      for (int u = 0; u < 8; ++u) o[i][u] += aij * vf[u];
    }
  }

  const f32x4 g0 = *(const f32x4*)&gamma[lane * 8];
  const f32x4 g1 = *(const f32x4*)&gamma[lane * 8 + 4];
  const f32x4 t0 = *(const f32x4*)&beta[lane * 8];
  const f32x4 t1 = *(const f32x4*)&beta[lane * 8 + 4];
  float gm[8] = {g0[0], g0[1], g0[2], g0[3], g1[0], g1[1], g1[2], g1[3]};
  float bt[8] = {t0[0], t0[1], t0[2], t0[3], t1[0], t1[1], t1[2], t1[3]};

  #pragma unroll
  for (int i = 0; i < NR; ++i) {
    float s1 = 0.f, s2 = 0.f;
    #pragma unroll
    for (int u = 0; u < 8; ++u) { s1 += o[i][u]; s2 += o[i][u] * o[i][u]; }
    #pragma unroll
    for (int m = 1; m < 64; m <<= 1) {
      s1 += __shfl_xor(s1, m, 64); s2 += __shfl_xor(s2, m, 64);
    }
    const float mu = s1 * (1.f / 512.f);
    const float rv = rsqrtf(s2 * (1.f / 512.f) - mu * mu + 1e-5f);
    const int zi = (MODE == 0) ? i : 8;
    const u16x8 z8 = *(const u16x8*)&z[(b9 + zi) * 512 + lane * 8];
    #pragma unroll
    for (int u = 0; u < 8; ++u)
      o[i][u] = bf2f(z8[u]) + gm[u] * (o[i][u] - mu) * rv + bt[u];
  }

  if (MODE == 0) {
    #pragma unroll
    for (int i = 0; i < 9; ++i) {
      const int srcn = (5 * i + 4) % 9;
      u16x8 ov;
      #pragma unroll
      for (int u = 0; u < 8; ++u) ov[u] = f2bf(0.5f * (o[i][u] + o[srcn][u]));
      *(u16x8*)&outp[(b9 + i) * 512 + lane * 8] = ov;
    }
  } else {
    u16x8 ov;
    #pragma unroll
    for (int u = 0; u < 8; ++u) ov[u] = f2bf(o[0][u]);
    *(u16x8*)&outp[b * 512 + lane * 8] = ov;
  }
}

// ---------------------------------------------------------------- launcher
extern "C" void kernel_launch(void* const* d_in, const int* in_sizes, int n_in,
                              void* d_out, int out_size, void* d_ws, size_t ws_size,
                              hipStream_t stream) {
  (void)in_sizes; (void)n_in; (void)out_size;
  const float* x      = (const float*)d_in[0];
  const float* W_in   = (const float*)d_in[1];
  const float* b_in   = (const float*)d_in[2];
  const float* W_dr   = (const float*)d_in[3];
  const float* b_dr   = (const float*)d_in[4];
  const float* W_hyp  = (const float*)d_in[5];
  const float* b_hyp  = (const float*)d_in[6];
  const float* Wq_r   = (const float*)d_in[7];
  const float* Wq_i   = (const float*)d_in[8];
  const float* Wq_j   = (const float*)d_in[9];
  const float* Wq_k   = (const float*)d_in[10];
  const float* b_quat = (const float*)d_in[11];
  const float* W_low  = (const float*)d_in[12];
  const float* W_high = (const float*)d_in[13];
  const float* b_wav  = (const float*)d_in[14];
  const float* aWq    = (const float*)d_in[15];
  const float* aWk    = (const float*)d_in[16];
  const float* aWv    = (const float*)d_in[17];
  const float* aWo    = (const float*)d_in[18];
  const float* gamma  = (const float*)d_in[19];
  const float* beta   = (const float*)d_in[20];
  const float* W_out  = (const float*)d_in[21];
  const float* b_out  = (const float*)d_in[22];
  float* out = (float*)d_out;

  // ---- workspace: [weights ~13.2 MB][per-chunk activations] ----
  char* ws = (char*)d_ws;
  char* wp = ws;
  u16* WinT   = (u16*)wp;  wp += (size_t)4608 * 512 * 2;
  u16* WdrT   = (u16*)wp;  wp += 524288;
  u16* WhyT   = (u16*)wp;  wp += 524288;
  u16* WquT   = (u16*)wp;  wp += 524288;
  u16* WwvT   = (u16*)wp;  wp += 524288;
  u16* BTqkvo = (u16*)wp;  wp += 3 * 1024 * 512 * 2;
  u16* WouT   = (u16*)wp;  wp += 131072;
  float* WoTf = (float*)wp; wp += 3 * 512 * 512 * 4;
  const size_t woff = (size_t)(wp - ws);

  int nc = 2;
  while (nc < 64 && woff + (size_t)(16384 / nc) * 37888ULL > ws_size) nc *= 2;
  const int CB = 16384 / nc;
  const int CR = CB * 9;

  char* cbase = ws + woff;
  u16* xbf  = (u16*)cbase;                       // CB x 512 (also nf8 out)
  u16* buf0 = (u16*)(cbase + (size_t)CB * 1024); // CR x 512
  u16* buf1 = buf0 + (size_t)CR * 512;           // CR x 512
  u16* sv   = buf1 + (size_t)CR * 512;           // CR x 1024 (also agg scratch)

  // ---- weight prep ----
  trans_conv<<<9216, 256, 0, stream>>>(W_in, WinT, 512, 4608, 1);
  trans_conv<<<1024, 256, 0, stream>>>(W_dr, WdrT, 512, 512, 1);
  trans_conv<<<1024, 256, 0, stream>>>(W_hyp, WhyT, 512, 512, 1);
  trans_conv<<<256, 256, 0, stream>>>(W_out, WouT, 512, 128, 1);
  build_quat<<<1024, 256, 0, stream>>>(Wq_r, Wq_i, Wq_j, Wq_k, WquT);
  build_wav<<<1024, 256, 0, stream>>>(W_low, W_high, WwvT);
  transf32<<<3072, 256, 0, stream>>>(aWo, WoTf);
  fold_nt<<<384, 256, 0, stream>>>(aWq, aWk, aWv, WoTf, BTqkvo);

  const int g512 = (CR >> 8) * 2;               // (CR,512) gemm256 grid
  const int g1024 = (CR >> 8) * 4;              // (CR,1024) gemm256 grid
  const int rowsDiv4 = CR >> 2;

  for (int c = 0; c < nc; ++c) {
    const size_t b0 = (size_t)c * CB;
    conv_bf<<<CB * 2, 256, 0, stream>>>(x + b0 * 512, xbf, (long)CB * 512);
    // p = leaky(x@W_in+b_in)   (M=CB, N=4608)
    gemm256<1><<<(CB >> 8) * 18, 512, 0, stream>>>(
        xbf, WinT, buf0, b_in, 4608, 512);
    // nf = tanh(p@W_dr+b_dr)
    gemm256<2><<<g512, 512, 0, stream>>>(buf0, WdrT, buf1, b_dr, 512, 512);
    agg_k<<<rowsDiv4, 256, 0, stream>>>(buf1, sv);   // sv as scratch
    // z = tanh(agg@W_hyp+b_hyp)
    gemm256<2><<<g512, 512, 0, stream>>>(sv, WhyT, buf0, b_hyp, 512, 512);

    for (int l = 0; l < 3; ++l) {
      // [s|vo] = z @ [Wqk | Wvo]   (N=1024)
      gemm256<0><<<g1024, 512, 0, stream>>>(
          buf0, BTqkvo + (size_t)l * 524288, sv, nullptr, 1024, 512);
      if (l < 2) {
        attn_fused<0><<<CB / 4, 256, 0, stream>>>(
            sv, buf0, gamma + l * 512, beta + l * 512, buf1);
        gemm256<2><<<g512, 512, 0, stream>>>(
            buf1, (l == 0) ? WquT : WwvT, buf0,
            (l == 0) ? b_quat : b_wav, 512, 512);
      } else {
        attn_fused<2><<<CB / 4, 256, 0, stream>>>(
            sv, buf0, gamma + 2 * 512, beta + 2 * 512, xbf);
      }
    }
    // out = nf8 @ W_out + b_out  (f32, N=128 -> 128-tile kernel)
    gemm_k<3><<<CB >> 7, 256, 0, stream>>>(
        xbf, 512, WouT, nullptr, out + b0 * 128, b_out, 128, 512);
  }
}